// Round 10
// baseline (191.502 us; speedup 1.0000x reference)
//
#include <hip/hip_runtime.h>
#include <math.h>

#define NT 262144
#define KD 512
#define NE 64
#define DE 64

constexpr int BM = 128;       // tokens per block
constexpr int NS = KD / 32;   // 16 K-steps
constexpr int WS_EN = 49152;  // u32 offset of e_norm bf16-split planes
constexpr int LT = 33;        // stage-2 per-wave transpose stride (floats)

using f32x4 = __attribute__((ext_vector_type(4))) float;
using s16x8 = __attribute__((ext_vector_type(8))) short;

typedef const __attribute__((address_space(1))) unsigned int* gp1_t;
typedef __attribute__((address_space(3))) unsigned int* lp3_t;

// ---- 3-term truncated bf16 split of fp32: x = x1 + x2 + x3, |res| <= 2^-24|x| ----
__device__ __forceinline__ void split8(float4 lo, float4 hi,
                                       s16x8& o1, s16x8& o2, s16x8& o3) {
    float x[8] = {lo.x, lo.y, lo.z, lo.w, hi.x, hi.y, hi.z, hi.w};
    union { unsigned int u[4]; s16x8 v; } r1, r2, r3;
    #pragma unroll
    for (int p = 0; p < 4; ++p) {
        float f0 = x[2 * p], f1 = x[2 * p + 1];
        unsigned int a = __float_as_uint(f0), b = __float_as_uint(f1);
        unsigned int a1 = a & 0xFFFF0000u, b1 = b & 0xFFFF0000u;
        r1.u[p] = (a1 >> 16) | b1;
        float q0 = f0 - __uint_as_float(a1);
        float q1 = f1 - __uint_as_float(b1);
        unsigned int a2 = __float_as_uint(q0) & 0xFFFF0000u;
        unsigned int b2 = __float_as_uint(q1) & 0xFFFF0000u;
        r2.u[p] = (a2 >> 16) | b2;
        float s0 = q0 - __uint_as_float(a2);
        float s1 = q1 - __uint_as_float(b2);
        r3.u[p] = (__float_as_uint(s0) >> 16) | (__float_as_uint(s1) & 0xFFFF0000u);
    }
    o1 = r1.v; o2 = r2.v; o3 = r3.v;
}

__device__ __forceinline__ s16x8 ld_frag(const unsigned int* p) {
    union { uint4 q; s16x8 v; } u;
    u.q = *(const uint4*)p;
    return u.v;
}

// ---- prep (unchanged from round 9) ----
__global__ void prep(const float* __restrict__ W, const float* __restrict__ E,
                     unsigned int* __restrict__ ws) {
    const int tid = threadIdx.x;
    if (blockIdx.x < 16) {
        const int idx = blockIdx.x * 256 + tid;     // chunk: row*64 + k8
        const int row = idx >> 6, k8 = idx & 63;
        const float* src = W + (size_t)row * KD + k8 * 8;
        float4 lo = *(const float4*)src, hi = *(const float4*)(src + 4);
        s16x8 o1, o2, o3;
        split8(lo, hi, o1, o2, o3);
        union { s16x8 v; uint4 q; } u1, u2, u3;
        u1.v = o1; u2.v = o2; u3.v = o3;
        const int ks = k8 >> 2, lk = k8 & 3, ct = row >> 4, lr = row & 15;
        const int g = ks * 4 + ct, lane = lk * 16 + lr;
        unsigned int* base = ws + (size_t)g * 768 + lane * 4;
        *(uint4*)(base)       = u1.q;
        *(uint4*)(base + 256) = u2.q;
        *(uint4*)(base + 512) = u3.q;
    } else {
        const int er = tid >> 2, part = tid & 3;    // expert row, d-quarter
        float ss = 0.f;
        float4 ev[4];
        #pragma unroll
        for (int u = 0; u < 4; ++u) {
            ev[u] = *(const float4*)(E + er * DE + part * 16 + u * 4);
            ss = fmaf(ev[u].x, ev[u].x, ss);
            ss = fmaf(ev[u].y, ev[u].y, ss);
            ss = fmaf(ev[u].z, ev[u].z, ss);
            ss = fmaf(ev[u].w, ev[u].w, ss);
        }
        ss += __shfl_xor(ss, 1, 64);
        ss += __shfl_xor(ss, 2, 64);
        const float inv_e = 1.0f / fmaxf(sqrtf(ss), 1e-12f);
        #pragma unroll
        for (int u = 0; u < 4; ++u) {
            ev[u].x *= inv_e; ev[u].y *= inv_e; ev[u].z *= inv_e; ev[u].w *= inv_e;
        }
        #pragma unroll
        for (int half = 0; half < 2; ++half) {      // 8 consecutive d each
            const int d0 = part * 16 + half * 8;
            s16x8 o1, o2, o3;
            split8(ev[half * 2], ev[half * 2 + 1], o1, o2, o3);
            union { s16x8 v; uint4 q; } u1, u2, u3;
            u1.v = o1; u2.v = o2; u3.v = o3;
            const int k2 = d0 >> 5, kg = (d0 >> 3) & 3;
            const int ge = k2 * 4 + (er >> 4), l = (er & 15) | (kg << 4);
            unsigned int* base = ws + WS_EN + (size_t)ge * 768 + l * 4;
            *(uint4*)(base)       = u1.q;
            *(uint4*)(base + 256) = u2.q;
            *(uint4*)(base + 512) = u3.q;
        }
    }
}

// ---- fused main ----
// LDS cut 40->28KB => 5 blocks/CU (20 waves, +25% TLP; occupancy was the
// untested lever -- all pipes <40% busy at 4 blocks):
//  * B SINGLE-buffered (12KB): barrier2 after the MFMA cluster, then issue
//    B[k+1] -- B is L2-hot (~300cy), the step-end->step-top gap covers it.
//  * Split waits: issue order per step is A(k+1) then B(k+1), so vmcnt(3)
//    at step top retires A(k) (reads+split overlap B's landing) and
//    vmcnt(4) before barrier1 retires B(k), leaving A(k+1) in flight.
//    tau preloaded+drained first so no stray VMEM corrupts the counts.
//  * stage-2 transpose chunked through per-wave-private 4.2KB regions in
//    d-halves -> no 34.8KB h_norm overlay.
//  * s_setprio(1) around MFMA clusters (T5: 5 de-phased blocks/CU).
// LDS: [0,3072) B | [3072,7168) A slices | stage-2 scratch reuses [0,4224).
__global__ __launch_bounds__(256, 5) void moe_all(const float* __restrict__ h,
                                                  const unsigned int* __restrict__ wsW,
                                                  const float* __restrict__ tau_p,
                                                  float* __restrict__ out) {
    __shared__ float smem[7168];   // 28KB

    const int tid = threadIdx.x;
    const int lane = tid & 63;
    const int wv = tid >> 6;          // wave 0..3 -> tokens [wv*32, wv*32+32)
    const int lr = lane & 15;         // fragment row/col within 16
    const int lk = lane >> 4;         // k-group 0..3
    const long tok0 = (long)blockIdx.x * BM;

    // preload tau and drain, so the K-loop's counted vmcnt sees ONLY DMA ops
    const float inv_tau_pre = 1.0f / tau_p[0];
    asm volatile("s_waitcnt vmcnt(0)" ::: "memory");

    f32x4 acc[2][4];                  // stage-1 [row-tile][col-tile]
    #pragma unroll
    for (int rt = 0; rt < 2; ++rt)
        #pragma unroll
        for (int ct = 0; ct < 4; ++ct)
            acc[rt][ct] = (f32x4){0.f, 0.f, 0.f, 0.f};

#define STAGE_A(KS)                                                            \
    {                                                                          \
        _Pragma("unroll")                                                      \
        for (int n = 0; n < 4; ++n) {                                          \
            const int flat = (wv * 4 + n) * 64 + lane;                         \
            const int t = flat >> 3, q = flat & 7;                             \
            const int qs = q ^ (t & 7);                                        \
            const float* g = h + (tok0 + t) * (long)KD + (KS) * 32 + qs * 4;   \
            float* l = smem + 3072 + wv * 1024 + n * 256;                      \
            __builtin_amdgcn_global_load_lds((gp1_t)(const void*)g,            \
                                             (lp3_t)(void*)l, 16, 0, 0);       \
        }                                                                      \
    }

#define STAGE_B(KS)                                                            \
    {                                                                          \
        _Pragma("unroll")                                                      \
        for (int i = 0; i < 3; ++i) {                                          \
            const unsigned int* g = wsW + (size_t)(KS) * 3072 + i * 1024       \
                                    + wv * 256 + lane * 4;                     \
            float* l = smem + i * 1024 + wv * 256;                             \
            __builtin_amdgcn_global_load_lds((gp1_t)(const void*)g,            \
                                             (lp3_t)(void*)l, 16, 0, 0);       \
        }                                                                      \
    }

// One K-step. Queue at top: [A(KS):4 oldest, B(KS):3].
#define PHASE(KS, LAST)                                                        \
    {                                                                          \
        asm volatile("s_waitcnt vmcnt(3)" ::: "memory");   /* A(KS) landed */  \
        float4 xl0 = *(const float4*)(abase + lr * 32 + q0 * 4);               \
        float4 xh0 = *(const float4*)(abase + lr * 32 + q1 * 4);               \
        float4 xl1 = *(const float4*)(abase + (lr + 16) * 32 + q0 * 4);        \
        float4 xh1 = *(const float4*)(abase + (lr + 16) * 32 + q1 * 4);        \
        asm volatile("s_waitcnt lgkmcnt(0)" ::: "memory"); /* A buf free */    \
        if (!(LAST)) { STAGE_A((KS) + 1); }                                    \
        __builtin_amdgcn_sched_barrier(0);                                     \
        s16x8 a1[2], a2[2], a3[2];                                             \
        split8(xl0, xh0, a1[0], a2[0], a3[0]);                                 \
        split8(xl1, xh1, a1[1], a2[1], a3[1]);                                 \
        if (LAST) { asm volatile("s_waitcnt vmcnt(0)" ::: "memory"); }         \
        else      { asm volatile("s_waitcnt vmcnt(4)" ::: "memory"); }         \
        __builtin_amdgcn_s_barrier();        /* everyone's B(KS) landed */     \
        __builtin_amdgcn_s_setprio(1);                                         \
        _Pragma("unroll")                                                      \
        for (int ct = 0; ct < 4; ++ct) {                                       \
            const unsigned int* bb =                                           \
                (const unsigned int*)(smem + ct * 768) + lane * 4;             \
            s16x8 b1 = ld_frag(bb);                                            \
            s16x8 b2 = ld_frag(bb + 256);                                      \
            s16x8 b3 = ld_frag(bb + 512);                                      \
            f32x4 c0 = acc[0][ct], c1 = acc[1][ct];                            \
            c0 = __builtin_amdgcn_mfma_f32_16x16x32_bf16(a1[0], b1, c0, 0, 0, 0); \
            c1 = __builtin_amdgcn_mfma_f32_16x16x32_bf16(a1[1], b1, c1, 0, 0, 0); \
            c0 = __builtin_amdgcn_mfma_f32_16x16x32_bf16(a2[0], b1, c0, 0, 0, 0); \
            c1 = __builtin_amdgcn_mfma_f32_16x16x32_bf16(a2[1], b1, c1, 0, 0, 0); \
            c0 = __builtin_amdgcn_mfma_f32_16x16x32_bf16(a1[0], b2, c0, 0, 0, 0); \
            c1 = __builtin_amdgcn_mfma_f32_16x16x32_bf16(a1[1], b2, c1, 0, 0, 0); \
            c0 = __builtin_amdgcn_mfma_f32_16x16x32_bf16(a3[0], b1, c0, 0, 0, 0); \
            c1 = __builtin_amdgcn_mfma_f32_16x16x32_bf16(a3[1], b1, c1, 0, 0, 0); \
            c0 = __builtin_amdgcn_mfma_f32_16x16x32_bf16(a2[0], b2, c0, 0, 0, 0); \
            c1 = __builtin_amdgcn_mfma_f32_16x16x32_bf16(a2[1], b2, c1, 0, 0, 0); \
            c0 = __builtin_amdgcn_mfma_f32_16x16x32_bf16(a1[0], b3, c0, 0, 0, 0); \
            c1 = __builtin_amdgcn_mfma_f32_16x16x32_bf16(a1[1], b3, c1, 0, 0, 0); \
            acc[0][ct] = c0; acc[1][ct] = c1;                                  \
        }                                                                      \
        __builtin_amdgcn_s_setprio(0);                                         \
        if (!(LAST)) {                                                         \
            __builtin_amdgcn_s_barrier();    /* all waves done reading B */    \
            STAGE_B((KS) + 1);               /* safe to overwrite */           \
        }                                                                      \
    }

    // prologue: A(0) first (oldest in queue), then B(0)
    STAGE_A(0);
    STAGE_B(0);
    __builtin_amdgcn_sched_barrier(0);

    const int sw = lr & 7;
    const int q0 = (lk * 2) ^ sw;
    const int q1 = (lk * 2 + 1) ^ sw;
    const float* abase = smem + 3072 + wv * 1024;

    for (int ks = 0; ks < NS - 1; ++ks) { PHASE(ks, 0); }
    PHASE(NS - 1, 1);

    // ---- per-token L2 norm from fragments ----
    // C/D layout: col = lane&15 (d), row = (lane>>4)*4 + reg (token within 16)
    float inv_n[2][4];
    #pragma unroll
    for (int rt = 0; rt < 2; ++rt) {
        #pragma unroll
        for (int r = 0; r < 4; ++r) {
            float ss = 0.f;
            #pragma unroll
            for (int ct = 0; ct < 4; ++ct)
                ss = fmaf(acc[rt][ct][r], acc[rt][ct][r], ss);
            ss += __shfl_xor(ss, 1, 64);
            ss += __shfl_xor(ss, 2, 64);
            ss += __shfl_xor(ss, 4, 64);
            ss += __shfl_xor(ss, 8, 64);
            inv_n[rt][r] = 1.0f / fmaxf(sqrtf(ss), 1e-12f);
        }
    }

    __syncthreads();   // all waves done with staging LDS; scratch reuse safe

    // ---- stage 2 (MFMA, chunked transpose): scores[32][64] per wave ----
    // Per-wave PRIVATE scratch: 32 tok x 33 floats at smem + wv*1056.
    // Two d-halves: write half (ct pair) -> read A-frags -> 24 MFMA; repeat.
    const unsigned int* wsE = wsW + WS_EN;
    float* wreg = smem + wv * 1056;
    f32x4 sc[2][4];                    // [rt][e-tile]
    #pragma unroll
    for (int rt = 0; rt < 2; ++rt)
        #pragma unroll
        for (int ce = 0; ce < 4; ++ce)
            sc[rt][ce] = (f32x4){0.f, 0.f, 0.f, 0.f};

    #pragma unroll
    for (int k2 = 0; k2 < 2; ++k2) {
        // write d-half: d_local = (ct-2*k2)*16 + lr, rows = rt*16 + lk*4 + r
        #pragma unroll
        for (int rt = 0; rt < 2; ++rt)
            #pragma unroll
            for (int cl = 0; cl < 2; ++cl)
                #pragma unroll
                for (int r = 0; r < 4; ++r) {
                    const int ct = k2 * 2 + cl;
                    wreg[(rt * 16 + lk * 4 + r) * LT + cl * 16 + lr] =
                        acc[rt][ct][r] * inv_n[rt][r];
                }
        // read A-frags (compiler orders LDS write->read on smem)
        s16x8 ha1[2], ha2[2], ha3[2];
        #pragma unroll
        for (int rt = 0; rt < 2; ++rt) {
            const float* ra = wreg + (rt * 16 + lr) * LT + lk * 8;
            float4 lo = *(const float4*)ra;
            float4 hi = *(const float4*)(ra + 4);
            split8(lo, hi, ha1[rt], ha2[rt], ha3[rt]);
        }
        __builtin_amdgcn_s_setprio(1);
        #pragma unroll
        for (int ce = 0; ce < 4; ++ce) {
            const unsigned int* bb = wsE + (k2 * 4 + ce) * 768 + lane * 4;
            s16x8 b1 = ld_frag(bb);
            s16x8 b2 = ld_frag(bb + 256);
            s16x8 b3 = ld_frag(bb + 512);
            #pragma unroll
            for (int rt = 0; rt < 2; ++rt) {
                f32x4 c = sc[rt][ce];
                c = __builtin_amdgcn_mfma_f32_16x16x32_bf16(ha1[rt], b1, c, 0, 0, 0);
                c = __builtin_amdgcn_mfma_f32_16x16x32_bf16(ha2[rt], b1, c, 0, 0, 0);
                c = __builtin_amdgcn_mfma_f32_16x16x32_bf16(ha1[rt], b2, c, 0, 0, 0);
                c = __builtin_amdgcn_mfma_f32_16x16x32_bf16(ha3[rt], b1, c, 0, 0, 0);
                c = __builtin_amdgcn_mfma_f32_16x16x32_bf16(ha2[rt], b2, c, 0, 0, 0);
                c = __builtin_amdgcn_mfma_f32_16x16x32_bf16(ha1[rt], b3, c, 0, 0, 0);
                sc[rt][ce] = c;
            }
        }
        __builtin_amdgcn_s_setprio(0);
    }

    // ---- epilogue on C-fragment layout (unchanged from round 9) ----
    const float inv_tau = inv_tau_pre;
    float* outS = out;                        // sparse_gates [NT][64]
    float* outI = out + (size_t)NT * 64;      // topk_indices [NT][2] (as float)
    float* outF = out + (size_t)NT * 66;      // full_gates   [NT][64]

    #pragma unroll
    for (int rt = 0; rt < 2; ++rt) {
        #pragma unroll
        for (int r = 0; r < 4; ++r) {
            const long tok = tok0 + wv * 32 + rt * 16 + lk * 4 + r;
            float s[4];
            #pragma unroll
            for (int ce = 0; ce < 4; ++ce) s[ce] = sc[rt][ce][r] * inv_tau;

            float m = fmaxf(fmaxf(s[0], s[1]), fmaxf(s[2], s[3]));
            m = fmaxf(m, __shfl_xor(m, 1, 64));
            m = fmaxf(m, __shfl_xor(m, 2, 64));
            m = fmaxf(m, __shfl_xor(m, 4, 64));
            m = fmaxf(m, __shfl_xor(m, 8, 64));

            float g[4], z = 0.f;
            #pragma unroll
            for (int ce = 0; ce < 4; ++ce) { g[ce] = __expf(s[ce] - m); z += g[ce]; }
            z += __shfl_xor(z, 1, 64);
            z += __shfl_xor(z, 2, 64);
            z += __shfl_xor(z, 4, 64);
            z += __shfl_xor(z, 8, 64);
            const float invZ = 1.0f / z;

            #pragma unroll
            for (int ce = 0; ce < 4; ++ce)
                outF[tok * 64 + ce * 16 + lr] = g[ce] * invZ;

            // top-2 on s (monotone with gates); ties -> lower index (jax top_k)
            float v1 = -3.4e38f, v2 = -3.4e38f;
            int i1 = 1 << 20, i2 = 1 << 20;
            #pragma unroll
            for (int ce = 0; ce < 4; ++ce) {
                float v = s[ce];
                int e = ce * 16 + lr;
                if (v > v1 || (v == v1 && e < i1)) { v2 = v1; i2 = i1; v1 = v; i1 = e; }
                else if (v > v2 || (v == v2 && e < i2)) { v2 = v; i2 = e; }
            }
            #pragma unroll
            for (int msk = 1; msk <= 8; msk <<= 1) {
                float o1 = __shfl_xor(v1, msk, 64); int oi1 = __shfl_xor(i1, msk, 64);
                float o2 = __shfl_xor(v2, msk, 64); int oi2 = __shfl_xor(i2, msk, 64);
                if (o1 > v1 || (o1 == v1 && oi1 < i1)) {
                    if (v1 > o2 || (v1 == o2 && i1 < oi2)) { v2 = v1; i2 = i1; }
                    else { v2 = o2; i2 = oi2; }
                    v1 = o1; i1 = oi1;
                } else {
                    if (o1 > v2 || (o1 == v2 && oi1 < i2)) { v2 = o1; i2 = oi1; }
                }
            }

            // softmax over the two top GATE values
            float gv1 = __expf(v1 - m) * invZ;
            float gv2 = __expf(v2 - m) * invZ;
            float qq = __expf(gv2 - gv1);
            float w1 = 1.0f / (1.0f + qq);
            float w2 = qq * w1;

            #pragma unroll
            for (int ce = 0; ce < 4; ++ce) {
                int e = ce * 16 + lr;
                outS[tok * 64 + e] = (e == i1) ? w1 : ((e == i2) ? w2 : 0.0f);
            }
            if (lr == 0) {
                *(float2*)(outI + tok * 2) = make_float2((float)i1, (float)i2);
            }
        }
    }
#undef STAGE_A
#undef STAGE_B
#undef PHASE
}

extern "C" void kernel_launch(void* const* d_in, const int* in_sizes, int n_in,
                              void* d_out, int out_size, void* d_ws, size_t ws_size,
                              hipStream_t stream) {
    const float* h   = (const float*)d_in[0];
    const float* W   = (const float*)d_in[1];
    const float* E   = (const float*)d_in[2];
    const float* tau = (const float*)d_in[3];
    float* out = (float*)d_out;
    unsigned int* ws = (unsigned int*)d_ws;   // 192KB W frags + 24KB e_norm frags

    prep<<<17, 256, 0, stream>>>(W, E, ws);
    moe_all<<<NT / BM, 256, 0, stream>>>(h, ws, tau, out);
}

// Round 11
// 160.241 us; speedup vs baseline: 1.1951x; 1.1951x over previous
//
#include <hip/hip_runtime.h>
#include <hip/hip_fp16.h>
#include <math.h>

#define NT 262144
#define KD 512
#define NE 64
#define DE 64

constexpr int BM = 128;       // tokens per block
constexpr int NS = KD / 32;   // 16 K-steps
constexpr int WS_EN = 32768;  // u32 offset of e_norm f16-split planes
constexpr int LD2 = 68;       // h_norm [tok][d] stride (floats)
constexpr float RSC  = 4096.0f;          // residual-plane scale (2^12)
constexpr float IRSC = 1.0f / 4096.0f;

using f32x4 = __attribute__((ext_vector_type(4))) float;
using f16x8 = __attribute__((ext_vector_type(8))) _Float16;

typedef const __attribute__((address_space(1))) unsigned int* gp1_t;
typedef __attribute__((address_space(3))) unsigned int* lp3_t;

// ---- 2-term f16 split: x = a1 + a2s*2^-12 + eps, |eps| <= 2^-22|x| + 1.5e-8.
// a1 = f16(x); a2s = f16((x - a1) * 4096)  [scaling avoids f16 subnormals].
__device__ __forceinline__ void splitf16(float4 lo, float4 hi,
                                         f16x8& o1, f16x8& o2) {
    float x[8] = {lo.x, lo.y, lo.z, lo.w, hi.x, hi.y, hi.z, hi.w};
    union { unsigned int u[4]; f16x8 v; } r1, r2;
    #pragma unroll
    for (int p = 0; p < 4; ++p) {
        float f0 = x[2 * p], f1 = x[2 * p + 1];
        __half2 h1 = __float22half2_rn(make_float2(f0, f1));
        float2 bk = __half22float2(h1);
        __half2 h2 = __float22half2_rn(make_float2((f0 - bk.x) * RSC,
                                                   (f1 - bk.y) * RSC));
        r1.u[p] = *reinterpret_cast<unsigned int*>(&h1);
        r2.u[p] = *reinterpret_cast<unsigned int*>(&h2);
    }
    o1 = r1.v; o2 = r2.v;
}

__device__ __forceinline__ f16x8 ld_frag(const unsigned int* p) {
    union { uint4 q; f16x8 v; } u;
    u.q = *(const uint4*)p;
    return u.v;
}

// ---- prep ----
// blocks 0..15: W -> fragment-order f16 planes: group g = ks*4 + ct,
//   512 u32/group: {p1[64 lanes x 4u32], p2s[64 x 4]}. One K-step = 4 groups
//   = 8KB contiguous (the main kernel's per-step B DMA).
// block 16: e_norm -> same 2-plane fragment order at WS_EN (8 groups).
__global__ void prep(const float* __restrict__ W, const float* __restrict__ E,
                     unsigned int* __restrict__ ws) {
    const int tid = threadIdx.x;
    if (blockIdx.x < 16) {
        const int idx = blockIdx.x * 256 + tid;     // chunk: row*64 + k8
        const int row = idx >> 6, k8 = idx & 63;
        const float* src = W + (size_t)row * KD + k8 * 8;
        float4 lo = *(const float4*)src, hi = *(const float4*)(src + 4);
        f16x8 o1, o2;
        splitf16(lo, hi, o1, o2);
        union { f16x8 v; uint4 q; } u1, u2;
        u1.v = o1; u2.v = o2;
        const int ks = k8 >> 2, lk = k8 & 3, ct = row >> 4, lr = row & 15;
        const int g = ks * 4 + ct, lane = lk * 16 + lr;
        unsigned int* base = ws + (size_t)g * 512 + lane * 4;
        *(uint4*)(base)       = u1.q;
        *(uint4*)(base + 256) = u2.q;
    } else {
        const int er = tid >> 2, part = tid & 3;    // expert row, d-quarter
        float ss = 0.f;
        float4 ev[4];
        #pragma unroll
        for (int u = 0; u < 4; ++u) {
            ev[u] = *(const float4*)(E + er * DE + part * 16 + u * 4);
            ss = fmaf(ev[u].x, ev[u].x, ss);
            ss = fmaf(ev[u].y, ev[u].y, ss);
            ss = fmaf(ev[u].z, ev[u].z, ss);
            ss = fmaf(ev[u].w, ev[u].w, ss);
        }
        ss += __shfl_xor(ss, 1, 64);
        ss += __shfl_xor(ss, 2, 64);
        const float inv_e = 1.0f / fmaxf(sqrtf(ss), 1e-12f);
        #pragma unroll
        for (int u = 0; u < 4; ++u) {
            ev[u].x *= inv_e; ev[u].y *= inv_e; ev[u].z *= inv_e; ev[u].w *= inv_e;
        }
        #pragma unroll
        for (int half = 0; half < 2; ++half) {      // 8 consecutive d each
            const int d0 = part * 16 + half * 8;
            f16x8 o1, o2;
            splitf16(ev[half * 2], ev[half * 2 + 1], o1, o2);
            union { f16x8 v; uint4 q; } u1, u2;
            u1.v = o1; u2.v = o2;
            const int k2 = d0 >> 5, kg = (d0 >> 3) & 3;
            const int ge = k2 * 4 + (er >> 4), l = (er & 15) | (kg << 4);
            unsigned int* base = ws + WS_EN + (size_t)ge * 512 + l * 4;
            *(uint4*)(base)       = u1.q;
            *(uint4*)(base + 256) = u2.q;
        }
    }
}

// ---- fused main (round-9 structure; f16 2-plane split) ----
// Binder identified in r10 post-mortem: LDS read pipe ~100% (256 b128/CU per
// step-window ~= the 3.1K-cyc cadence). This round cuts LDS reads 25%
// (16 -> 12 b128/wave/step) and MFMAs 50% by moving from 3-plane bf16
// (6 products) to 2-plane f16 (3 products) with a scaled residual plane
// carried in a second accumulator (folded back as acc + acc2*2^-12).
// LDS: [0,4096) B dbuf 16KB | [4096,8192) A slices 16KB; h_norm overlay
// [tok][d] stride 68 (34.8KB) -> 4 blocks/CU.
__global__ __launch_bounds__(256, 4) void moe_all(const float* __restrict__ h,
                                                  const unsigned int* __restrict__ wsW,
                                                  const float* __restrict__ tau_p,
                                                  float* __restrict__ out) {
    __shared__ float smem[8704];

    const int tid = threadIdx.x;
    const int lane = tid & 63;
    const int wv = tid >> 6;          // wave 0..3 -> tokens [wv*32, wv*32+32)
    const int lr = lane & 15;         // fragment row/col within 16
    const int lk = lane >> 4;         // k-group 0..3
    const long tok0 = (long)blockIdx.x * BM;

    f32x4 acc[2][4], ac2[2][4];       // main + scaled-residual accumulators
    #pragma unroll
    for (int rt = 0; rt < 2; ++rt)
        #pragma unroll
        for (int ct = 0; ct < 4; ++ct) {
            acc[rt][ct] = (f32x4){0.f, 0.f, 0.f, 0.f};
            ac2[rt][ct] = (f32x4){0.f, 0.f, 0.f, 0.f};
        }

#define STAGE_A(KS)                                                            \
    {                                                                          \
        _Pragma("unroll")                                                      \
        for (int n = 0; n < 4; ++n) {                                          \
            const int flat = (wv * 4 + n) * 64 + lane;                         \
            const int t = flat >> 3, q = flat & 7;                             \
            const int qs = q ^ (t & 7);                                        \
            const float* g = h + (tok0 + t) * (long)KD + (KS) * 32 + qs * 4;   \
            float* l = smem + 4096 + wv * 1024 + n * 256;                      \
            __builtin_amdgcn_global_load_lds((gp1_t)(const void*)g,            \
                                             (lp3_t)(void*)l, 16, 0, 0);       \
        }                                                                      \
    }

#define STAGE_B(CUR, KS)                                                       \
    {                                                                          \
        _Pragma("unroll")                                                      \
        for (int i = 0; i < 2; ++i) {                                          \
            const unsigned int* g = wsW + (size_t)(KS) * 2048 + i * 1024       \
                                    + wv * 256 + lane * 4;                     \
            float* l = smem + (CUR) * 2048 + i * 1024 + wv * 256;              \
            __builtin_amdgcn_global_load_lds((gp1_t)(const void*)g,            \
                                             (lp3_t)(void*)l, 16, 0, 0);       \
        }                                                                      \
    }

    STAGE_B(0, 0);
    STAGE_A(0);

    const int sw = lr & 7;
    const int q0 = (lk * 2) ^ sw;
    const int q1 = (lk * 2 + 1) ^ sw;
    const float* abase = smem + 4096 + wv * 1024;

    for (int ks = 0; ks < NS; ++ks) {
        const int cur = ks & 1;
        asm volatile("s_waitcnt vmcnt(0)" ::: "memory");
        __builtin_amdgcn_s_barrier();
        if (ks + 1 < NS) { STAGE_B(cur ^ 1, ks + 1); }
        __builtin_amdgcn_sched_barrier(0);

        float4 xl0 = *(const float4*)(abase + lr * 32 + q0 * 4);
        float4 xh0 = *(const float4*)(abase + lr * 32 + q1 * 4);
        float4 xl1 = *(const float4*)(abase + (lr + 16) * 32 + q0 * 4);
        float4 xh1 = *(const float4*)(abase + (lr + 16) * 32 + q1 * 4);
        asm volatile("s_waitcnt lgkmcnt(0)" ::: "memory");
        if (ks + 1 < NS) { STAGE_A(ks + 1); }
        __builtin_amdgcn_sched_barrier(0);

        f16x8 a1[2], a2[2];
        splitf16(xl0, xh0, a1[0], a2[0]);
        splitf16(xl1, xh1, a1[1], a2[1]);

        #pragma unroll
        for (int ct = 0; ct < 4; ++ct) {
            const unsigned int* bb =
                (const unsigned int*)(smem + cur * 2048) + ct * 512 + lane * 4;
            f16x8 b1 = ld_frag(bb);
            f16x8 b2 = ld_frag(bb + 256);
            f32x4 c0 = acc[0][ct], c1 = acc[1][ct];
            f32x4 d0 = ac2[0][ct], d1 = ac2[1][ct];
            c0 = __builtin_amdgcn_mfma_f32_16x16x32_f16(a1[0], b1, c0, 0, 0, 0);
            c1 = __builtin_amdgcn_mfma_f32_16x16x32_f16(a1[1], b1, c1, 0, 0, 0);
            d0 = __builtin_amdgcn_mfma_f32_16x16x32_f16(a1[0], b2, d0, 0, 0, 0);
            d1 = __builtin_amdgcn_mfma_f32_16x16x32_f16(a1[1], b2, d1, 0, 0, 0);
            d0 = __builtin_amdgcn_mfma_f32_16x16x32_f16(a2[0], b1, d0, 0, 0, 0);
            d1 = __builtin_amdgcn_mfma_f32_16x16x32_f16(a2[1], b1, d1, 0, 0, 0);
            acc[0][ct] = c0; acc[1][ct] = c1;
            ac2[0][ct] = d0; ac2[1][ct] = d1;
        }
    }

    // fold the scaled-residual accumulator back: proj = acc + ac2 * 2^-12
    #pragma unroll
    for (int rt = 0; rt < 2; ++rt)
        #pragma unroll
        for (int ct = 0; ct < 4; ++ct)
            #pragma unroll
            for (int r = 0; r < 4; ++r)
                acc[rt][ct][r] = fmaf(ac2[rt][ct][r], IRSC, acc[rt][ct][r]);

    // ---- per-token L2 norm from fragments ----
    // C/D layout: col = lane&15 (d), row = (lane>>4)*4 + reg (token within 16)
    float inv_n[2][4];
    #pragma unroll
    for (int rt = 0; rt < 2; ++rt) {
        #pragma unroll
        for (int r = 0; r < 4; ++r) {
            float ss = 0.f;
            #pragma unroll
            for (int ct = 0; ct < 4; ++ct)
                ss = fmaf(acc[rt][ct][r], acc[rt][ct][r], ss);
            ss += __shfl_xor(ss, 1, 64);
            ss += __shfl_xor(ss, 2, 64);
            ss += __shfl_xor(ss, 4, 64);
            ss += __shfl_xor(ss, 8, 64);
            inv_n[rt][r] = 1.0f / fmaxf(sqrtf(ss), 1e-12f);
        }
    }

    __syncthreads();   // all waves done with staging LDS (h_norm overlays it)

    // h_norm -> smem as [tok][d], stride 68. Each wave writes and later reads
    // ONLY its own 32 tokens -> no 2nd sync.
    #pragma unroll
    for (int rt = 0; rt < 2; ++rt)
        #pragma unroll
        for (int ct = 0; ct < 4; ++ct)
            #pragma unroll
            for (int r = 0; r < 4; ++r) {
                const int t = wv * 32 + rt * 16 + lk * 4 + r;
                smem[t * LD2 + ct * 16 + lr] = acc[rt][ct][r] * inv_n[rt][r];
            }

    // ---- stage 2 (MFMA, f16 2-plane): scores[32][64] per wave ----
    const unsigned int* wsE = wsW + WS_EN;
    f32x4 sc[2][4], sc2[2][4];
    #pragma unroll
    for (int rt = 0; rt < 2; ++rt)
        #pragma unroll
        for (int ce = 0; ce < 4; ++ce) {
            sc[rt][ce]  = (f32x4){0.f, 0.f, 0.f, 0.f};
            sc2[rt][ce] = (f32x4){0.f, 0.f, 0.f, 0.f};
        }

    #pragma unroll
    for (int k2 = 0; k2 < 2; ++k2) {
        f16x8 ha1[2], ha2[2];
        #pragma unroll
        for (int rt = 0; rt < 2; ++rt) {
            const float* ra = smem + (wv * 32 + rt * 16 + lr) * LD2 + k2 * 32 + lk * 8;
            float4 lo = *(const float4*)ra;
            float4 hi = *(const float4*)(ra + 4);
            splitf16(lo, hi, ha1[rt], ha2[rt]);
        }
        #pragma unroll
        for (int ce = 0; ce < 4; ++ce) {
            const unsigned int* bb = wsE + (k2 * 4 + ce) * 512 + lane * 4;
            f16x8 b1 = ld_frag(bb);
            f16x8 b2 = ld_frag(bb + 256);
            #pragma unroll
            for (int rt = 0; rt < 2; ++rt) {
                f32x4 c = sc[rt][ce], d = sc2[rt][ce];
                c = __builtin_amdgcn_mfma_f32_16x16x32_f16(ha1[rt], b1, c, 0, 0, 0);
                d = __builtin_amdgcn_mfma_f32_16x16x32_f16(ha1[rt], b2, d, 0, 0, 0);
                d = __builtin_amdgcn_mfma_f32_16x16x32_f16(ha2[rt], b1, d, 0, 0, 0);
                sc[rt][ce] = c; sc2[rt][ce] = d;
            }
        }
    }

    // ---- epilogue on C-fragment layout ----
    // Lane holds, for token = wv*32 + rt*16 + lk*4 + reg, experts e = ce*16+lr.
    const float inv_tau = 1.0f / tau_p[0];
    float* outS = out;                        // sparse_gates [NT][64]
    float* outI = out + (size_t)NT * 64;      // topk_indices [NT][2] (as float)
    float* outF = out + (size_t)NT * 66;      // full_gates   [NT][64]

    #pragma unroll
    for (int rt = 0; rt < 2; ++rt) {
        #pragma unroll
        for (int r = 0; r < 4; ++r) {
            const long tok = tok0 + wv * 32 + rt * 16 + lk * 4 + r;
            float s[4];
            #pragma unroll
            for (int ce = 0; ce < 4; ++ce)
                s[ce] = fmaf(sc2[rt][ce][r], IRSC, sc[rt][ce][r]) * inv_tau;

            float m = fmaxf(fmaxf(s[0], s[1]), fmaxf(s[2], s[3]));
            m = fmaxf(m, __shfl_xor(m, 1, 64));
            m = fmaxf(m, __shfl_xor(m, 2, 64));
            m = fmaxf(m, __shfl_xor(m, 4, 64));
            m = fmaxf(m, __shfl_xor(m, 8, 64));

            float g[4], z = 0.f;
            #pragma unroll
            for (int ce = 0; ce < 4; ++ce) { g[ce] = __expf(s[ce] - m); z += g[ce]; }
            z += __shfl_xor(z, 1, 64);
            z += __shfl_xor(z, 2, 64);
            z += __shfl_xor(z, 4, 64);
            z += __shfl_xor(z, 8, 64);
            const float invZ = 1.0f / z;

            #pragma unroll
            for (int ce = 0; ce < 4; ++ce)
                outF[tok * 64 + ce * 16 + lr] = g[ce] * invZ;

            // top-2 on s (monotone with gates); ties -> lower index (jax top_k)
            float v1 = -3.4e38f, v2 = -3.4e38f;
            int i1 = 1 << 20, i2 = 1 << 20;
            #pragma unroll
            for (int ce = 0; ce < 4; ++ce) {
                float v = s[ce];
                int e = ce * 16 + lr;
                if (v > v1 || (v == v1 && e < i1)) { v2 = v1; i2 = i1; v1 = v; i1 = e; }
                else if (v > v2 || (v == v2 && e < i2)) { v2 = v; i2 = e; }
            }
            #pragma unroll
            for (int msk = 1; msk <= 8; msk <<= 1) {
                float o1 = __shfl_xor(v1, msk, 64); int oi1 = __shfl_xor(i1, msk, 64);
                float o2 = __shfl_xor(v2, msk, 64); int oi2 = __shfl_xor(i2, msk, 64);
                if (o1 > v1 || (o1 == v1 && oi1 < i1)) {
                    if (v1 > o2 || (v1 == o2 && i1 < oi2)) { v2 = v1; i2 = i1; }
                    else { v2 = o2; i2 = oi2; }
                    v1 = o1; i1 = oi1;
                } else {
                    if (o1 > v2 || (o1 == v2 && oi1 < i2)) { v2 = o1; i2 = oi1; }
                }
            }

            // softmax over the two top GATE values
            float gv1 = __expf(v1 - m) * invZ;
            float gv2 = __expf(v2 - m) * invZ;
            float qq = __expf(gv2 - gv1);
            float w1 = 1.0f / (1.0f + qq);
            float w2 = qq * w1;

            #pragma unroll
            for (int ce = 0; ce < 4; ++ce) {
                int e = ce * 16 + lr;
                outS[tok * 64 + e] = (e == i1) ? w1 : ((e == i2) ? w2 : 0.0f);
            }
            if (lr == 0) {
                *(float2*)(outI + tok * 2) = make_float2((float)i1, (float)i2);
            }
        }
    }
#undef STAGE_A
#undef STAGE_B
}

extern "C" void kernel_launch(void* const* d_in, const int* in_sizes, int n_in,
                              void* d_out, int out_size, void* d_ws, size_t ws_size,
                              hipStream_t stream) {
    const float* h   = (const float*)d_in[0];
    const float* W   = (const float*)d_in[1];
    const float* E   = (const float*)d_in[2];
    const float* tau = (const float*)d_in[3];
    float* out = (float*)d_out;
    unsigned int* ws = (unsigned int*)d_ws;   // 128KB W frags + 16KB e_norm frags

    prep<<<17, 256, 0, stream>>>(W, E, ws);
    moe_all<<<NT / BM, 256, 0, stream>>>(h, ws, tau, out);
}

// Round 12
// 152.715 us; speedup vs baseline: 1.2540x; 1.0493x over previous
//
#include <hip/hip_runtime.h>
#include <hip/hip_fp16.h>
#include <math.h>

#define NT 262144
#define KD 512
#define NE 64
#define DE 64

constexpr int BM = 128;       // tokens per block
constexpr int NS = KD / 32;   // 16 K-steps
constexpr int WS_EN = 32768;  // u32 offset of e_norm f16-split planes
constexpr int LD2 = 68;       // h_norm [tok][d] stride (floats)
constexpr float RSC  = 4096.0f;          // residual-plane scale (2^12)
constexpr float IRSC = 1.0f / 4096.0f;

using f32x4 = __attribute__((ext_vector_type(4))) float;
using f16x8 = __attribute__((ext_vector_type(8))) _Float16;

typedef const __attribute__((address_space(1))) unsigned int* gp1_t;
typedef __attribute__((address_space(3))) unsigned int* lp3_t;

// ---- 2-term f16 split: x = a1 + a2s*2^-12 + eps, |eps| <= 2^-22|x| + 1.5e-8.
__device__ __forceinline__ void splitf16(float4 lo, float4 hi,
                                         f16x8& o1, f16x8& o2) {
    float x[8] = {lo.x, lo.y, lo.z, lo.w, hi.x, hi.y, hi.z, hi.w};
    union { unsigned int u[4]; f16x8 v; } r1, r2;
    #pragma unroll
    for (int p = 0; p < 4; ++p) {
        float f0 = x[2 * p], f1 = x[2 * p + 1];
        __half2 h1 = __float22half2_rn(make_float2(f0, f1));
        float2 bk = __half22float2(h1);
        __half2 h2 = __float22half2_rn(make_float2((f0 - bk.x) * RSC,
                                                   (f1 - bk.y) * RSC));
        r1.u[p] = *reinterpret_cast<unsigned int*>(&h1);
        r2.u[p] = *reinterpret_cast<unsigned int*>(&h2);
    }
    o1 = r1.v; o2 = r2.v;
}

__device__ __forceinline__ f16x8 ld_frag(const unsigned int* p) {
    union { uint4 q; f16x8 v; } u;
    u.q = *(const uint4*)p;
    return u.v;
}

// ---- prep (unchanged from round 11) ----
__global__ void prep(const float* __restrict__ W, const float* __restrict__ E,
                     unsigned int* __restrict__ ws) {
    const int tid = threadIdx.x;
    if (blockIdx.x < 16) {
        const int idx = blockIdx.x * 256 + tid;     // chunk: row*64 + k8
        const int row = idx >> 6, k8 = idx & 63;
        const float* src = W + (size_t)row * KD + k8 * 8;
        float4 lo = *(const float4*)src, hi = *(const float4*)(src + 4);
        f16x8 o1, o2;
        splitf16(lo, hi, o1, o2);
        union { f16x8 v; uint4 q; } u1, u2;
        u1.v = o1; u2.v = o2;
        const int ks = k8 >> 2, lk = k8 & 3, ct = row >> 4, lr = row & 15;
        const int g = ks * 4 + ct, lane = lk * 16 + lr;
        unsigned int* base = ws + (size_t)g * 512 + lane * 4;
        *(uint4*)(base)       = u1.q;
        *(uint4*)(base + 256) = u2.q;
    } else {
        const int er = tid >> 2, part = tid & 3;    // expert row, d-quarter
        float ss = 0.f;
        float4 ev[4];
        #pragma unroll
        for (int u = 0; u < 4; ++u) {
            ev[u] = *(const float4*)(E + er * DE + part * 16 + u * 4);
            ss = fmaf(ev[u].x, ev[u].x, ss);
            ss = fmaf(ev[u].y, ev[u].y, ss);
            ss = fmaf(ev[u].z, ev[u].z, ss);
            ss = fmaf(ev[u].w, ev[u].w, ss);
        }
        ss += __shfl_xor(ss, 1, 64);
        ss += __shfl_xor(ss, 2, 64);
        const float inv_e = 1.0f / fmaxf(sqrtf(ss), 1e-12f);
        #pragma unroll
        for (int u = 0; u < 4; ++u) {
            ev[u].x *= inv_e; ev[u].y *= inv_e; ev[u].z *= inv_e; ev[u].w *= inv_e;
        }
        #pragma unroll
        for (int half = 0; half < 2; ++half) {      // 8 consecutive d each
            const int d0 = part * 16 + half * 8;
            f16x8 o1, o2;
            splitf16(ev[half * 2], ev[half * 2 + 1], o1, o2);
            union { f16x8 v; uint4 q; } u1, u2;
            u1.v = o1; u2.v = o2;
            const int k2 = d0 >> 5, kg = (d0 >> 3) & 3;
            const int ge = k2 * 4 + (er >> 4), l = (er & 15) | (kg << 4);
            unsigned int* base = ws + WS_EN + (size_t)ge * 512 + l * 4;
            *(uint4*)(base)       = u1.q;
            *(uint4*)(base + 256) = u2.q;
        }
    }
}

// ---- fused main (round-11 structure; u64-key top-2 epilogue) ----
// K-loop untouched from r11 (measured best). Epilogue top-2 now merges
// order-preserving u64 keys: key = (ord(score) << 6) | (63 - e); max-by-key
// == (value desc, index asc) -- comparator-identical to jax top_k, ~4x fewer
// VALU per merge step than the float/int comparator tree.
__global__ __launch_bounds__(256, 4) void moe_all(const float* __restrict__ h,
                                                  const unsigned int* __restrict__ wsW,
                                                  const float* __restrict__ tau_p,
                                                  float* __restrict__ out) {
    __shared__ float smem[8704];

    const int tid = threadIdx.x;
    const int lane = tid & 63;
    const int wv = tid >> 6;          // wave 0..3 -> tokens [wv*32, wv*32+32)
    const int lr = lane & 15;         // fragment row/col within 16
    const int lk = lane >> 4;         // k-group 0..3
    const long tok0 = (long)blockIdx.x * BM;

    f32x4 acc[2][4], ac2[2][4];       // main + scaled-residual accumulators
    #pragma unroll
    for (int rt = 0; rt < 2; ++rt)
        #pragma unroll
        for (int ct = 0; ct < 4; ++ct) {
            acc[rt][ct] = (f32x4){0.f, 0.f, 0.f, 0.f};
            ac2[rt][ct] = (f32x4){0.f, 0.f, 0.f, 0.f};
        }

#define STAGE_A(KS)                                                            \
    {                                                                          \
        _Pragma("unroll")                                                      \
        for (int n = 0; n < 4; ++n) {                                          \
            const int flat = (wv * 4 + n) * 64 + lane;                         \
            const int t = flat >> 3, q = flat & 7;                             \
            const int qs = q ^ (t & 7);                                        \
            const float* g = h + (tok0 + t) * (long)KD + (KS) * 32 + qs * 4;   \
            float* l = smem + 4096 + wv * 1024 + n * 256;                      \
            __builtin_amdgcn_global_load_lds((gp1_t)(const void*)g,            \
                                             (lp3_t)(void*)l, 16, 0, 0);       \
        }                                                                      \
    }

#define STAGE_B(CUR, KS)                                                       \
    {                                                                          \
        _Pragma("unroll")                                                      \
        for (int i = 0; i < 2; ++i) {                                          \
            const unsigned int* g = wsW + (size_t)(KS) * 2048 + i * 1024       \
                                    + wv * 256 + lane * 4;                     \
            float* l = smem + (CUR) * 2048 + i * 1024 + wv * 256;              \
            __builtin_amdgcn_global_load_lds((gp1_t)(const void*)g,            \
                                             (lp3_t)(void*)l, 16, 0, 0);       \
        }                                                                      \
    }

    STAGE_B(0, 0);
    STAGE_A(0);

    const int sw = lr & 7;
    const int q0 = (lk * 2) ^ sw;
    const int q1 = (lk * 2 + 1) ^ sw;
    const float* abase = smem + 4096 + wv * 1024;

    for (int ks = 0; ks < NS; ++ks) {
        const int cur = ks & 1;
        asm volatile("s_waitcnt vmcnt(0)" ::: "memory");
        __builtin_amdgcn_s_barrier();
        if (ks + 1 < NS) { STAGE_B(cur ^ 1, ks + 1); }
        __builtin_amdgcn_sched_barrier(0);

        float4 xl0 = *(const float4*)(abase + lr * 32 + q0 * 4);
        float4 xh0 = *(const float4*)(abase + lr * 32 + q1 * 4);
        float4 xl1 = *(const float4*)(abase + (lr + 16) * 32 + q0 * 4);
        float4 xh1 = *(const float4*)(abase + (lr + 16) * 32 + q1 * 4);
        asm volatile("s_waitcnt lgkmcnt(0)" ::: "memory");
        if (ks + 1 < NS) { STAGE_A(ks + 1); }
        __builtin_amdgcn_sched_barrier(0);

        f16x8 a1[2], a2[2];
        splitf16(xl0, xh0, a1[0], a2[0]);
        splitf16(xl1, xh1, a1[1], a2[1]);

        #pragma unroll
        for (int ct = 0; ct < 4; ++ct) {
            const unsigned int* bb =
                (const unsigned int*)(smem + cur * 2048) + ct * 512 + lane * 4;
            f16x8 b1 = ld_frag(bb);
            f16x8 b2 = ld_frag(bb + 256);
            f32x4 c0 = acc[0][ct], c1 = acc[1][ct];
            f32x4 d0 = ac2[0][ct], d1 = ac2[1][ct];
            c0 = __builtin_amdgcn_mfma_f32_16x16x32_f16(a1[0], b1, c0, 0, 0, 0);
            c1 = __builtin_amdgcn_mfma_f32_16x16x32_f16(a1[1], b1, c1, 0, 0, 0);
            d0 = __builtin_amdgcn_mfma_f32_16x16x32_f16(a1[0], b2, d0, 0, 0, 0);
            d1 = __builtin_amdgcn_mfma_f32_16x16x32_f16(a1[1], b2, d1, 0, 0, 0);
            d0 = __builtin_amdgcn_mfma_f32_16x16x32_f16(a2[0], b1, d0, 0, 0, 0);
            d1 = __builtin_amdgcn_mfma_f32_16x16x32_f16(a2[1], b1, d1, 0, 0, 0);
            acc[0][ct] = c0; acc[1][ct] = c1;
            ac2[0][ct] = d0; ac2[1][ct] = d1;
        }
    }

    // fold the scaled-residual accumulator back: proj = acc + ac2 * 2^-12
    #pragma unroll
    for (int rt = 0; rt < 2; ++rt)
        #pragma unroll
        for (int ct = 0; ct < 4; ++ct)
            #pragma unroll
            for (int r = 0; r < 4; ++r)
                acc[rt][ct][r] = fmaf(ac2[rt][ct][r], IRSC, acc[rt][ct][r]);

    // ---- per-token L2 norm from fragments ----
    float inv_n[2][4];
    #pragma unroll
    for (int rt = 0; rt < 2; ++rt) {
        #pragma unroll
        for (int r = 0; r < 4; ++r) {
            float ss = 0.f;
            #pragma unroll
            for (int ct = 0; ct < 4; ++ct)
                ss = fmaf(acc[rt][ct][r], acc[rt][ct][r], ss);
            ss += __shfl_xor(ss, 1, 64);
            ss += __shfl_xor(ss, 2, 64);
            ss += __shfl_xor(ss, 4, 64);
            ss += __shfl_xor(ss, 8, 64);
            inv_n[rt][r] = 1.0f / fmaxf(sqrtf(ss), 1e-12f);
        }
    }

    __syncthreads();   // all waves done with staging LDS (h_norm overlays it)

    // h_norm -> smem as [tok][d], stride 68; each wave touches only its tokens
    #pragma unroll
    for (int rt = 0; rt < 2; ++rt)
        #pragma unroll
        for (int ct = 0; ct < 4; ++ct)
            #pragma unroll
            for (int r = 0; r < 4; ++r) {
                const int t = wv * 32 + rt * 16 + lk * 4 + r;
                smem[t * LD2 + ct * 16 + lr] = acc[rt][ct][r] * inv_n[rt][r];
            }

    // ---- stage 2 (MFMA, f16 2-plane): scores[32][64] per wave ----
    const unsigned int* wsE = wsW + WS_EN;
    f32x4 sc[2][4], sc2[2][4];
    #pragma unroll
    for (int rt = 0; rt < 2; ++rt)
        #pragma unroll
        for (int ce = 0; ce < 4; ++ce) {
            sc[rt][ce]  = (f32x4){0.f, 0.f, 0.f, 0.f};
            sc2[rt][ce] = (f32x4){0.f, 0.f, 0.f, 0.f};
        }

    #pragma unroll
    for (int k2 = 0; k2 < 2; ++k2) {
        f16x8 ha1[2], ha2[2];
        #pragma unroll
        for (int rt = 0; rt < 2; ++rt) {
            const float* ra = smem + (wv * 32 + rt * 16 + lr) * LD2 + k2 * 32 + lk * 8;
            float4 lo = *(const float4*)ra;
            float4 hi = *(const float4*)(ra + 4);
            splitf16(lo, hi, ha1[rt], ha2[rt]);
        }
        #pragma unroll
        for (int ce = 0; ce < 4; ++ce) {
            const unsigned int* bb = wsE + (k2 * 4 + ce) * 512 + lane * 4;
            f16x8 b1 = ld_frag(bb);
            f16x8 b2 = ld_frag(bb + 256);
            #pragma unroll
            for (int rt = 0; rt < 2; ++rt) {
                f32x4 c = sc[rt][ce], d = sc2[rt][ce];
                c = __builtin_amdgcn_mfma_f32_16x16x32_f16(ha1[rt], b1, c, 0, 0, 0);
                d = __builtin_amdgcn_mfma_f32_16x16x32_f16(ha1[rt], b2, d, 0, 0, 0);
                d = __builtin_amdgcn_mfma_f32_16x16x32_f16(ha2[rt], b1, d, 0, 0, 0);
                sc[rt][ce] = c; sc2[rt][ce] = d;
            }
        }
    }

    // ---- epilogue on C-fragment layout; u64-key top-2 ----
    const float inv_tau = 1.0f / tau_p[0];
    float* outS = out;                        // sparse_gates [NT][64]
    float* outI = out + (size_t)NT * 64;      // topk_indices [NT][2] (as float)
    float* outF = out + (size_t)NT * 66;      // full_gates   [NT][64]

    #pragma unroll
    for (int rt = 0; rt < 2; ++rt) {
        #pragma unroll
        for (int r = 0; r < 4; ++r) {
            const long tok = tok0 + wv * 32 + rt * 16 + lk * 4 + r;
            float s[4];
            #pragma unroll
            for (int ce = 0; ce < 4; ++ce)
                s[ce] = fmaf(sc2[rt][ce][r], IRSC, sc[rt][ce][r]) * inv_tau;

            float m = fmaxf(fmaxf(s[0], s[1]), fmaxf(s[2], s[3]));
            m = fmaxf(m, __shfl_xor(m, 1, 64));
            m = fmaxf(m, __shfl_xor(m, 2, 64));
            m = fmaxf(m, __shfl_xor(m, 4, 64));
            m = fmaxf(m, __shfl_xor(m, 8, 64));

            float g[4], z = 0.f;
            #pragma unroll
            for (int ce = 0; ce < 4; ++ce) { g[ce] = __expf(s[ce] - m); z += g[ce]; }
            z += __shfl_xor(z, 1, 64);
            z += __shfl_xor(z, 2, 64);
            z += __shfl_xor(z, 4, 64);
            z += __shfl_xor(z, 8, 64);
            const float invZ = 1.0f / z;

            #pragma unroll
            for (int ce = 0; ce < 4; ++ce)
                outF[tok * 64 + ce * 16 + lr] = g[ce] * invZ;

            // top-2 via order-preserving u64 keys: (ord(v) << 6) | (63 - e).
            // max-by-key == (value desc, index asc) -- jax top_k tie semantics.
            unsigned long long k1 = 0ULL, k2 = 0ULL;   // 0 < any real key
            #pragma unroll
            for (int ce = 0; ce < 4; ++ce) {
                unsigned int ou = __float_as_uint(s[ce]);
                ou = (ou & 0x80000000u) ? ~ou : (ou | 0x80000000u);
                unsigned long long key = ((unsigned long long)ou << 6)
                                       | (unsigned long long)(63 - (ce * 16 + lr));
                if (key > k1) { k2 = k1; k1 = key; }
                else if (key > k2) { k2 = key; }
            }
            #pragma unroll
            for (int msk = 1; msk <= 8; msk <<= 1) {
                unsigned long long o1 = __shfl_xor(k1, msk, 64);
                unsigned long long o2 = __shfl_xor(k2, msk, 64);
                unsigned long long hi = k1 > o1 ? k1 : o1;
                unsigned long long lo = k1 > o1 ? o1 : k1;
                unsigned long long m2 = k2 > o2 ? k2 : o2;
                k2 = lo > m2 ? lo : m2;
                k1 = hi;
            }
            const int i1 = 63 - (int)(k1 & 63ULL);
            const int i2 = 63 - (int)(k2 & 63ULL);
            const unsigned int u1 = (unsigned int)(k1 >> 6);
            const unsigned int u2 = (unsigned int)(k2 >> 6);
            const float v1 = __uint_as_float((u1 & 0x80000000u) ? (u1 ^ 0x80000000u) : ~u1);
            const float v2 = __uint_as_float((u2 & 0x80000000u) ? (u2 ^ 0x80000000u) : ~u2);

            // softmax over the two top GATE values
            float gv1 = __expf(v1 - m) * invZ;
            float gv2 = __expf(v2 - m) * invZ;
            float qq = __expf(gv2 - gv1);
            float w1 = 1.0f / (1.0f + qq);
            float w2 = qq * w1;

            #pragma unroll
            for (int ce = 0; ce < 4; ++ce) {
                int e = ce * 16 + lr;
                outS[tok * 64 + e] = (e == i1) ? w1 : ((e == i2) ? w2 : 0.0f);
            }
            if (lr == 0) {
                *(float2*)(outI + tok * 2) = make_float2((float)i1, (float)i2);
            }
        }
    }
#undef STAGE_A
#undef STAGE_B
}

extern "C" void kernel_launch(void* const* d_in, const int* in_sizes, int n_in,
                              void* d_out, int out_size, void* d_ws, size_t ws_size,
                              hipStream_t stream) {
    const float* h   = (const float*)d_in[0];
    const float* W   = (const float*)d_in[1];
    const float* E   = (const float*)d_in[2];
    const float* tau = (const float*)d_in[3];
    float* out = (float*)d_out;
    unsigned int* ws = (unsigned int*)d_ws;   // 128KB W frags + 16KB e_norm frags

    prep<<<17, 256, 0, stream>>>(W, E, ws);
    moe_all<<<NT / BM, 256, 0, stream>>>(h, ws, tau, out);
}

// Round 13
// 151.228 us; speedup vs baseline: 1.2663x; 1.0098x over previous
//
#include <hip/hip_runtime.h>
#include <hip/hip_fp16.h>
#include <math.h>

#define NT 262144
#define KD 512
#define NE 64
#define DE 64

constexpr int BM = 128;       // tokens per block
constexpr int NS = KD / 32;   // 16 K-steps
constexpr int WS_EN = 32768;  // u32 offset of e_norm f16-split planes
constexpr int LD2 = 68;       // h_norm [tok][d] stride (floats)
constexpr float RSC  = 4096.0f;          // residual-plane scale (2^12)
constexpr float IRSC = 1.0f / 4096.0f;

using f32x4 = __attribute__((ext_vector_type(4))) float;
using f16x8 = __attribute__((ext_vector_type(8))) _Float16;

typedef const __attribute__((address_space(1))) unsigned int* gp1_t;
typedef __attribute__((address_space(3))) unsigned int* lp3_t;

// ---- 2-term f16 split: x = a1 + a2s*2^-12 + eps, |eps| <= 2^-22|x| + 1.5e-8.
__device__ __forceinline__ void splitf16(float4 lo, float4 hi,
                                         f16x8& o1, f16x8& o2) {
    float x[8] = {lo.x, lo.y, lo.z, lo.w, hi.x, hi.y, hi.z, hi.w};
    union { unsigned int u[4]; f16x8 v; } r1, r2;
    #pragma unroll
    for (int p = 0; p < 4; ++p) {
        float f0 = x[2 * p], f1 = x[2 * p + 1];
        __half2 h1 = __float22half2_rn(make_float2(f0, f1));
        float2 bk = __half22float2(h1);
        __half2 h2 = __float22half2_rn(make_float2((f0 - bk.x) * RSC,
                                                   (f1 - bk.y) * RSC));
        r1.u[p] = *reinterpret_cast<unsigned int*>(&h1);
        r2.u[p] = *reinterpret_cast<unsigned int*>(&h2);
    }
    o1 = r1.v; o2 = r2.v;
}

__device__ __forceinline__ f16x8 ld_frag(const unsigned int* p) {
    union { uint4 q; f16x8 v; } u;
    u.q = *(const uint4*)p;
    return u.v;
}

// ---- prep (unchanged from round 12) ----
__global__ void prep(const float* __restrict__ W, const float* __restrict__ E,
                     unsigned int* __restrict__ ws) {
    const int tid = threadIdx.x;
    if (blockIdx.x < 16) {
        const int idx = blockIdx.x * 256 + tid;     // chunk: row*64 + k8
        const int row = idx >> 6, k8 = idx & 63;
        const float* src = W + (size_t)row * KD + k8 * 8;
        float4 lo = *(const float4*)src, hi = *(const float4*)(src + 4);
        f16x8 o1, o2;
        splitf16(lo, hi, o1, o2);
        union { f16x8 v; uint4 q; } u1, u2;
        u1.v = o1; u2.v = o2;
        const int ks = k8 >> 2, lk = k8 & 3, ct = row >> 4, lr = row & 15;
        const int g = ks * 4 + ct, lane = lk * 16 + lr;
        unsigned int* base = ws + (size_t)g * 512 + lane * 4;
        *(uint4*)(base)       = u1.q;
        *(uint4*)(base + 256) = u2.q;
    } else {
        const int er = tid >> 2, part = tid & 3;    // expert row, d-quarter
        float ss = 0.f;
        float4 ev[4];
        #pragma unroll
        for (int u = 0; u < 4; ++u) {
            ev[u] = *(const float4*)(E + er * DE + part * 16 + u * 4);
            ss = fmaf(ev[u].x, ev[u].x, ss);
            ss = fmaf(ev[u].y, ev[u].y, ss);
            ss = fmaf(ev[u].z, ev[u].z, ss);
            ss = fmaf(ev[u].w, ev[u].w, ss);
        }
        ss += __shfl_xor(ss, 1, 64);
        ss += __shfl_xor(ss, 2, 64);
        const float inv_e = 1.0f / fmaxf(sqrtf(ss), 1e-12f);
        #pragma unroll
        for (int u = 0; u < 4; ++u) {
            ev[u].x *= inv_e; ev[u].y *= inv_e; ev[u].z *= inv_e; ev[u].w *= inv_e;
        }
        #pragma unroll
        for (int half = 0; half < 2; ++half) {      // 8 consecutive d each
            const int d0 = part * 16 + half * 8;
            f16x8 o1, o2;
            splitf16(ev[half * 2], ev[half * 2 + 1], o1, o2);
            union { f16x8 v; uint4 q; } u1, u2;
            u1.v = o1; u2.v = o2;
            const int k2 = d0 >> 5, kg = (d0 >> 3) & 3;
            const int ge = k2 * 4 + (er >> 4), l = (er & 15) | (kg << 4);
            unsigned int* base = ws + WS_EN + (size_t)ge * 512 + l * 4;
            *(uint4*)(base)       = u1.q;
            *(uint4*)(base + 256) = u2.q;
        }
    }
}

// ---- fused main (round-12 structure; epilogue: top-2 first, m = v1) ----
// Exact identities: softmax max m == v1 (top-1 score), so the u64 top-2 merge
// runs FIRST and the separate max-reduction is deleted; gv1 = exp(v1-m)*invZ
// == invZ exactly (v1-m == 0.0), deleting one transcendental per row.
// Bit-exact vs round 12.
__global__ __launch_bounds__(256, 4) void moe_all(const float* __restrict__ h,
                                                  const unsigned int* __restrict__ wsW,
                                                  const float* __restrict__ tau_p,
                                                  float* __restrict__ out) {
    __shared__ float smem[8704];

    const int tid = threadIdx.x;
    const int lane = tid & 63;
    const int wv = tid >> 6;          // wave 0..3 -> tokens [wv*32, wv*32+32)
    const int lr = lane & 15;         // fragment row/col within 16
    const int lk = lane >> 4;         // k-group 0..3
    const long tok0 = (long)blockIdx.x * BM;

    f32x4 acc[2][4], ac2[2][4];       // main + scaled-residual accumulators
    #pragma unroll
    for (int rt = 0; rt < 2; ++rt)
        #pragma unroll
        for (int ct = 0; ct < 4; ++ct) {
            acc[rt][ct] = (f32x4){0.f, 0.f, 0.f, 0.f};
            ac2[rt][ct] = (f32x4){0.f, 0.f, 0.f, 0.f};
        }

#define STAGE_A(KS)                                                            \
    {                                                                          \
        _Pragma("unroll")                                                      \
        for (int n = 0; n < 4; ++n) {                                          \
            const int flat = (wv * 4 + n) * 64 + lane;                         \
            const int t = flat >> 3, q = flat & 7;                             \
            const int qs = q ^ (t & 7);                                        \
            const float* g = h + (tok0 + t) * (long)KD + (KS) * 32 + qs * 4;   \
            float* l = smem + 4096 + wv * 1024 + n * 256;                      \
            __builtin_amdgcn_global_load_lds((gp1_t)(const void*)g,            \
                                             (lp3_t)(void*)l, 16, 0, 0);       \
        }                                                                      \
    }

#define STAGE_B(CUR, KS)                                                       \
    {                                                                          \
        _Pragma("unroll")                                                      \
        for (int i = 0; i < 2; ++i) {                                          \
            const unsigned int* g = wsW + (size_t)(KS) * 2048 + i * 1024       \
                                    + wv * 256 + lane * 4;                     \
            float* l = smem + (CUR) * 2048 + i * 1024 + wv * 256;              \
            __builtin_amdgcn_global_load_lds((gp1_t)(const void*)g,            \
                                             (lp3_t)(void*)l, 16, 0, 0);       \
        }                                                                      \
    }

    STAGE_B(0, 0);
    STAGE_A(0);

    const int sw = lr & 7;
    const int q0 = (lk * 2) ^ sw;
    const int q1 = (lk * 2 + 1) ^ sw;
    const float* abase = smem + 4096 + wv * 1024;

    for (int ks = 0; ks < NS; ++ks) {
        const int cur = ks & 1;
        asm volatile("s_waitcnt vmcnt(0)" ::: "memory");
        __builtin_amdgcn_s_barrier();
        if (ks + 1 < NS) { STAGE_B(cur ^ 1, ks + 1); }
        __builtin_amdgcn_sched_barrier(0);

        float4 xl0 = *(const float4*)(abase + lr * 32 + q0 * 4);
        float4 xh0 = *(const float4*)(abase + lr * 32 + q1 * 4);
        float4 xl1 = *(const float4*)(abase + (lr + 16) * 32 + q0 * 4);
        float4 xh1 = *(const float4*)(abase + (lr + 16) * 32 + q1 * 4);
        asm volatile("s_waitcnt lgkmcnt(0)" ::: "memory");
        if (ks + 1 < NS) { STAGE_A(ks + 1); }
        __builtin_amdgcn_sched_barrier(0);

        f16x8 a1[2], a2[2];
        splitf16(xl0, xh0, a1[0], a2[0]);
        splitf16(xl1, xh1, a1[1], a2[1]);

        #pragma unroll
        for (int ct = 0; ct < 4; ++ct) {
            const unsigned int* bb =
                (const unsigned int*)(smem + cur * 2048) + ct * 512 + lane * 4;
            f16x8 b1 = ld_frag(bb);
            f16x8 b2 = ld_frag(bb + 256);
            f32x4 c0 = acc[0][ct], c1 = acc[1][ct];
            f32x4 d0 = ac2[0][ct], d1 = ac2[1][ct];
            c0 = __builtin_amdgcn_mfma_f32_16x16x32_f16(a1[0], b1, c0, 0, 0, 0);
            c1 = __builtin_amdgcn_mfma_f32_16x16x32_f16(a1[1], b1, c1, 0, 0, 0);
            d0 = __builtin_amdgcn_mfma_f32_16x16x32_f16(a1[0], b2, d0, 0, 0, 0);
            d1 = __builtin_amdgcn_mfma_f32_16x16x32_f16(a1[1], b2, d1, 0, 0, 0);
            d0 = __builtin_amdgcn_mfma_f32_16x16x32_f16(a2[0], b1, d0, 0, 0, 0);
            d1 = __builtin_amdgcn_mfma_f32_16x16x32_f16(a2[1], b1, d1, 0, 0, 0);
            acc[0][ct] = c0; acc[1][ct] = c1;
            ac2[0][ct] = d0; ac2[1][ct] = d1;
        }
    }

    // fold the scaled-residual accumulator back: proj = acc + ac2 * 2^-12
    #pragma unroll
    for (int rt = 0; rt < 2; ++rt)
        #pragma unroll
        for (int ct = 0; ct < 4; ++ct)
            #pragma unroll
            for (int r = 0; r < 4; ++r)
                acc[rt][ct][r] = fmaf(ac2[rt][ct][r], IRSC, acc[rt][ct][r]);

    // ---- per-token L2 norm from fragments ----
    float inv_n[2][4];
    #pragma unroll
    for (int rt = 0; rt < 2; ++rt) {
        #pragma unroll
        for (int r = 0; r < 4; ++r) {
            float ss = 0.f;
            #pragma unroll
            for (int ct = 0; ct < 4; ++ct)
                ss = fmaf(acc[rt][ct][r], acc[rt][ct][r], ss);
            ss += __shfl_xor(ss, 1, 64);
            ss += __shfl_xor(ss, 2, 64);
            ss += __shfl_xor(ss, 4, 64);
            ss += __shfl_xor(ss, 8, 64);
            inv_n[rt][r] = 1.0f / fmaxf(sqrtf(ss), 1e-12f);
        }
    }

    __syncthreads();   // all waves done with staging LDS (h_norm overlays it)

    // h_norm -> smem as [tok][d], stride 68; each wave touches only its tokens
    #pragma unroll
    for (int rt = 0; rt < 2; ++rt)
        #pragma unroll
        for (int ct = 0; ct < 4; ++ct)
            #pragma unroll
            for (int r = 0; r < 4; ++r) {
                const int t = wv * 32 + rt * 16 + lk * 4 + r;
                smem[t * LD2 + ct * 16 + lr] = acc[rt][ct][r] * inv_n[rt][r];
            }

    // ---- stage 2 (MFMA, f16 2-plane): scores[32][64] per wave ----
    const unsigned int* wsE = wsW + WS_EN;
    f32x4 sc[2][4], sc2[2][4];
    #pragma unroll
    for (int rt = 0; rt < 2; ++rt)
        #pragma unroll
        for (int ce = 0; ce < 4; ++ce) {
            sc[rt][ce]  = (f32x4){0.f, 0.f, 0.f, 0.f};
            sc2[rt][ce] = (f32x4){0.f, 0.f, 0.f, 0.f};
        }

    #pragma unroll
    for (int k2 = 0; k2 < 2; ++k2) {
        f16x8 ha1[2], ha2[2];
        #pragma unroll
        for (int rt = 0; rt < 2; ++rt) {
            const float* ra = smem + (wv * 32 + rt * 16 + lr) * LD2 + k2 * 32 + lk * 8;
            float4 lo = *(const float4*)ra;
            float4 hi = *(const float4*)(ra + 4);
            splitf16(lo, hi, ha1[rt], ha2[rt]);
        }
        #pragma unroll
        for (int ce = 0; ce < 4; ++ce) {
            const unsigned int* bb = wsE + (k2 * 4 + ce) * 512 + lane * 4;
            f16x8 b1 = ld_frag(bb);
            f16x8 b2 = ld_frag(bb + 256);
            #pragma unroll
            for (int rt = 0; rt < 2; ++rt) {
                f32x4 c = sc[rt][ce], d = sc2[rt][ce];
                c = __builtin_amdgcn_mfma_f32_16x16x32_f16(ha1[rt], b1, c, 0, 0, 0);
                d = __builtin_amdgcn_mfma_f32_16x16x32_f16(ha1[rt], b2, d, 0, 0, 0);
                d = __builtin_amdgcn_mfma_f32_16x16x32_f16(ha2[rt], b1, d, 0, 0, 0);
                sc[rt][ce] = c; sc2[rt][ce] = d;
            }
        }
    }

    // ---- epilogue on C-fragment layout; top-2 first, m = v1 ----
    const float inv_tau = 1.0f / tau_p[0];
    float* outS = out;                        // sparse_gates [NT][64]
    float* outI = out + (size_t)NT * 64;      // topk_indices [NT][2] (as float)
    float* outF = out + (size_t)NT * 66;      // full_gates   [NT][64]

    #pragma unroll
    for (int rt = 0; rt < 2; ++rt) {
        #pragma unroll
        for (int r = 0; r < 4; ++r) {
            const long tok = tok0 + wv * 32 + rt * 16 + lk * 4 + r;
            float s[4];
            #pragma unroll
            for (int ce = 0; ce < 4; ++ce)
                s[ce] = fmaf(sc2[rt][ce][r], IRSC, sc[rt][ce][r]) * inv_tau;

            // top-2 via order-preserving u64 keys: (ord(v) << 6) | (63 - e).
            // max-by-key == (value desc, index asc) -- jax top_k tie semantics.
            unsigned long long k1 = 0ULL, k2 = 0ULL;   // 0 < any real key
            #pragma unroll
            for (int ce = 0; ce < 4; ++ce) {
                unsigned int ou = __float_as_uint(s[ce]);
                ou = (ou & 0x80000000u) ? ~ou : (ou | 0x80000000u);
                unsigned long long key = ((unsigned long long)ou << 6)
                                       | (unsigned long long)(63 - (ce * 16 + lr));
                if (key > k1) { k2 = k1; k1 = key; }
                else if (key > k2) { k2 = key; }
            }
            #pragma unroll
            for (int msk = 1; msk <= 8; msk <<= 1) {
                unsigned long long o1 = __shfl_xor(k1, msk, 64);
                unsigned long long o2 = __shfl_xor(k2, msk, 64);
                unsigned long long hi = k1 > o1 ? k1 : o1;
                unsigned long long lo = k1 > o1 ? o1 : k1;
                unsigned long long m2 = k2 > o2 ? k2 : o2;
                k2 = lo > m2 ? lo : m2;
                k1 = hi;
            }
            const int i1 = 63 - (int)(k1 & 63ULL);
            const int i2 = 63 - (int)(k2 & 63ULL);
            const unsigned int u1 = (unsigned int)(k1 >> 6);
            const unsigned int u2 = (unsigned int)(k2 >> 6);
            const float v1 = __uint_as_float((u1 & 0x80000000u) ? (u1 ^ 0x80000000u) : ~u1);
            const float v2 = __uint_as_float((u2 & 0x80000000u) ? (u2 ^ 0x80000000u) : ~u2);

            // softmax max == v1 (top-1 score): no separate max-reduction
            const float m = v1;

            float g[4], z = 0.f;
            #pragma unroll
            for (int ce = 0; ce < 4; ++ce) { g[ce] = __expf(s[ce] - m); z += g[ce]; }
            z += __shfl_xor(z, 1, 64);
            z += __shfl_xor(z, 2, 64);
            z += __shfl_xor(z, 4, 64);
            z += __shfl_xor(z, 8, 64);
            const float invZ = 1.0f / z;

            #pragma unroll
            for (int ce = 0; ce < 4; ++ce)
                outF[tok * 64 + ce * 16 + lr] = g[ce] * invZ;

            // softmax over the two top GATE values; gv1 = exp(0)*invZ = invZ
            const float gv1 = invZ;
            const float gv2 = __expf(v2 - m) * invZ;
            const float qq = __expf(gv2 - gv1);
            const float w1 = 1.0f / (1.0f + qq);
            const float w2 = qq * w1;

            #pragma unroll
            for (int ce = 0; ce < 4; ++ce) {
                int e = ce * 16 + lr;
                outS[tok * 64 + e] = (e == i1) ? w1 : ((e == i2) ? w2 : 0.0f);
            }
            if (lr == 0) {
                *(float2*)(outI + tok * 2) = make_float2((float)i1, (float)i2);
            }
        }
    }
#undef STAGE_A
#undef STAGE_B
}

extern "C" void kernel_launch(void* const* d_in, const int* in_sizes, int n_in,
                              void* d_out, int out_size, void* d_ws, size_t ws_size,
                              hipStream_t stream) {
    const float* h   = (const float*)d_in[0];
    const float* W   = (const float*)d_in[1];
    const float* E   = (const float*)d_in[2];
    const float* tau = (const float*)d_in[3];
    float* out = (float*)d_out;
    unsigned int* ws = (unsigned int*)d_ws;   // 128KB W frags + 16KB e_norm frags

    prep<<<17, 256, 0, stream>>>(W, E, ws);
    moe_all<<<NT / BM, 256, 0, stream>>>(h, ws, tau, out);
}